// Round 9
// baseline (400.491 us; speedup 1.0000x reference)
//
#include <hip/hip_runtime.h>
#include <math.h>

#define IN_DIM 256
#define FDIM 256      // HEADS*HID == OUT == 256
#define HEADS 4
#define NEG 0.2f
#define MAXD 96       // per-node staged edge cap; in-deg ~ Poisson(16)+1, P(>96) ~ 0

typedef __attribute__((ext_vector_type(8))) short bf16x8;
typedef __attribute__((ext_vector_type(8))) unsigned short u16x8;
typedef __attribute__((ext_vector_type(4))) float f32x4;

__device__ __forceinline__ float leaky(float x){ return x > 0.f ? x : NEG * x; }

__device__ __forceinline__ unsigned short f2bf(float f){
  unsigned int u = __float_as_uint(f);
  unsigned int r = u + 0x7fffu + ((u >> 16) & 1u);   // round-to-nearest-even
  return (unsigned short)(r >> 16);
}
__device__ __forceinline__ float bf2f(unsigned short s){
  return __uint_as_float(((unsigned int)s) << 16);
}

__device__ __forceinline__ float4 bcast4(float4 v){
  return make_float4(__shfl(v.x,0,64), __shfl(v.y,0,64), __shfl(v.z,0,64), __shfl(v.w,0,64));
}
__device__ __forceinline__ float comp4(float4 v, int h){
  return h==0 ? v.x : h==1 ? v.y : h==2 ? v.z : v.w;
}

__device__ __forceinline__ void gld_lds16(const void* g, void* l){
  __builtin_amdgcn_global_load_lds((const __attribute__((address_space(1))) unsigned int*)g,
                                   (__attribute__((address_space(3))) unsigned int*)l, 16, 0, 0);
}

// ------------------------- fused: W1/W2 transpose-cast (LDS, coalesced) + degree histogram -------------------------
__global__ void k_wthist(const float* __restrict__ W1, unsigned short* __restrict__ W1t,
                         const float* __restrict__ W2, unsigned short* __restrict__ W2t,
                         const int* __restrict__ dst, int* __restrict__ deg, int E){
  int b = blockIdx.x;
  if (b < 32){
    __shared__ float tile[64][65];
    const float* W = (b < 16) ? W1 : W2;
    unsigned short* Wt = (b < 16) ? W1t : W2t;
    int bb = b & 15;
    int tk = (bb >> 2) * 64, tn = (bb & 3) * 64;   // 4x4 grid of 64x64 tiles
    int t = threadIdx.x;
    int cr = t >> 6, cc = t & 63;                  // wave-row, lane-col
    #pragma unroll
    for (int r = 0; r < 16; ++r){
      int k = r * 4 + cr;
      tile[k][cc] = W[(size_t)(tk + k) * 256 + tn + cc];   // coalesced 256B/wave
    }
    __syncthreads();
    #pragma unroll
    for (int r = 0; r < 16; ++r){
      int nn = r * 4 + cr;
      Wt[(size_t)(tn + nn) * 256 + tk + cc] = f2bf(tile[cc][nn]);  // pad(65) -> conflict-free
    }
  } else {
    int e = (b - 32) * 256 + threadIdx.x;
    if (e < E) atomicAdd(&deg[dst[e]], 1);
  }
}

// ------------------------- CSR build -------------------------
__global__ void k_scanA(const int* __restrict__ deg, int* tmp, int* partials, int n){
  __shared__ int sm[256];
  int i = blockIdx.x * 256 + threadIdx.x;
  int v = (i < n) ? deg[i] + 1 : 0;     // +1: self loop
  sm[threadIdx.x] = v; __syncthreads();
  for (int off = 1; off < 256; off <<= 1){
    int x = (threadIdx.x >= off) ? sm[threadIdx.x - off] : 0;
    __syncthreads();
    sm[threadIdx.x] += x;
    __syncthreads();
  }
  if (i < n) tmp[i] = sm[threadIdx.x];            // inclusive within block
  if (threadIdx.x == 255) partials[blockIdx.x] = sm[255];
}

// scanC with inline partials-prefix reduction (nb <= 256)
__global__ void k_scanC(const int* __restrict__ tmp, const int* __restrict__ deg,
                        const int* __restrict__ partials, int* rowptr, int n, int nb){
  __shared__ int ws[4];
  int bid = blockIdx.x, t = threadIdx.x;
  int lane = t & 63, w = t >> 6;
  int v = (t < bid && t < nb) ? partials[t] : 0;
  #pragma unroll
  for (int off = 32; off >= 1; off >>= 1) v += __shfl_down(v, off, 64);
  if (lane == 0) ws[w] = v;
  __syncthreads();
  int prefix = ws[0] + ws[1] + ws[2] + ws[3];
  int i = bid * 256 + t;
  if (i < n){
    int incl = tmp[i] + prefix;
    rowptr[i] = incl - (deg[i] + 1);
    if (i == n - 1) rowptr[n] = incl;             // total = E + n
  }
}

__global__ void k_fill(const int* __restrict__ src, const int* __restrict__ dst,
                       const int* __restrict__ rowptr, int* fill, int* col, int E, int n){
  int e = blockIdx.x * blockDim.x + threadIdx.x;
  if (e < E + n){
    int s, d;
    if (e < E){ s = src[e]; d = dst[e]; } else { s = d = e - E; }
    int pos = atomicAdd(&fill[d], 1);
    col[rowptr[d] + pos] = s;
  }
}

// ------------------------- bf16 MFMA GEMM 1: C[M,256] = cast_bf16(X[M,256] fp32) @ Bt^T -------------------------
// A staged from fp32 via registers (cast fused; removes the standalone cast pass).
__global__ __launch_bounds__(256) void k_gemm1(const float* __restrict__ X,
                                               const unsigned short* __restrict__ Bt,
                                               unsigned short* __restrict__ C, int n){
  __shared__ __align__(16) unsigned short sh[8192];   // As = sh[0:4096], Bs = sh[4096:8192]
  unsigned short* As = sh;
  unsigned short* Bs = sh + 4096;
  int tid = threadIdx.x;
  int lane = tid & 63, wave = tid >> 6;
  int rowBase = blockIdx.x * 128, colBase = blockIdx.y * 128;
  int wr = (wave & 1) * 64, wc = (wave >> 1) * 64;

  f32x4 acc[4][4] = {};
  int c0 = tid, c1 = tid + 256;
  int r0 = c0 >> 2, kc0 = (c0 & 3) * 8;
  int r1 = c1 >> 2, kc1 = (c1 & 3) * 8;
  int m0 = lane & 15, kq = (lane >> 4) * 8;
  int ra = rowBase + r0; if (ra >= n) ra = n - 1;   // clamp: padded rows feed unused C rows
  int rb = rowBase + r1; if (rb >= n) rb = n - 1;

  for (int k0 = 0; k0 < 256; k0 += 32){
    // A: fp32 -> bf16 reg staging (2 segments of 8 elems per thread)
    float4 va0 = *(const float4*)(X + (size_t)ra * 256 + k0 + kc0);
    float4 va1 = *(const float4*)(X + (size_t)ra * 256 + k0 + kc0 + 4);
    float4 vb0 = *(const float4*)(X + (size_t)rb * 256 + k0 + kc1);
    float4 vb1 = *(const float4*)(X + (size_t)rb * 256 + k0 + kc1 + 4);
    u16x8 sa, sb;
    sa[0]=f2bf(va0.x); sa[1]=f2bf(va0.y); sa[2]=f2bf(va0.z); sa[3]=f2bf(va0.w);
    sa[4]=f2bf(va1.x); sa[5]=f2bf(va1.y); sa[6]=f2bf(va1.z); sa[7]=f2bf(va1.w);
    sb[0]=f2bf(vb0.x); sb[1]=f2bf(vb0.y); sb[2]=f2bf(vb0.z); sb[3]=f2bf(vb0.w);
    sb[4]=f2bf(vb1.x); sb[5]=f2bf(vb1.y); sb[6]=f2bf(vb1.z); sb[7]=f2bf(vb1.w);
    *(u16x8*)(As + c0 * 8) = sa;          // As[r0*32 + kc0]
    *(u16x8*)(As + c1 * 8) = sb;
    gld_lds16(Bt + (size_t)(colBase + r0) * 256 + k0 + kc0, (char*)Bs + c0 * 16);
    gld_lds16(Bt + (size_t)(colBase + r1) * 256 + k0 + kc1, (char*)Bs + c1 * 16);
    __syncthreads();
    bf16x8 af[4], bfr[4];
    #pragma unroll
    for (int it = 0; it < 4; ++it)
      af[it] = *(const bf16x8*)(As + (wr + it * 16 + m0) * 32 + kq);
    #pragma unroll
    for (int jt = 0; jt < 4; ++jt)
      bfr[jt] = *(const bf16x8*)(Bs + (wc + jt * 16 + m0) * 32 + kq);
    #pragma unroll
    for (int it = 0; it < 4; ++it)
      #pragma unroll
      for (int jt = 0; jt < 4; ++jt)
        acc[it][jt] = __builtin_amdgcn_mfma_f32_16x16x32_bf16(af[it], bfr[jt], acc[it][jt], 0, 0, 0);
    __syncthreads();
  }
  int cq = lane >> 4, cm = lane & 15;
  #pragma unroll
  for (int p = 0; p < 2; ++p){
    if ((wave >> 1) == p){
      #pragma unroll
      for (int it = 0; it < 4; ++it)
        #pragma unroll
        for (int jt = 0; jt < 4; ++jt)
          #pragma unroll
          for (int r = 0; r < 4; ++r)
            sh[(wr + it * 16 + cq * 4 + r) * 64 + jt * 16 + cm] = f2bf(acc[it][jt][r]);
    }
    __syncthreads();
    #pragma unroll
    for (int q = 0; q < 4; ++q){
      int id = tid + q * 256;
      int r = id >> 3, sg = id & 7;
      u16x8 v = *(const u16x8*)(sh + r * 64 + sg * 8);
      *(u16x8*)(C + (size_t)(rowBase + r) * 256 + colBase + p * 64 + sg * 8) = v;
    }
    __syncthreads();
  }
}

// ------------------------- bf16 MFMA GEMM: C[M,256] = A[M,256] @ Bt[256,256]^T -------------------------
__global__ __launch_bounds__(256) void k_gemm(const unsigned short* __restrict__ A,
                                              const unsigned short* __restrict__ Bt,
                                              unsigned short* __restrict__ C){
  __shared__ __align__(16) unsigned short sh[8192];   // As = sh[0:4096], Bs = sh[4096:8192] (shorts)
  unsigned short* As = sh;
  unsigned short* Bs = sh + 4096;
  int tid = threadIdx.x;
  int lane = tid & 63, wave = tid >> 6;
  int rowBase = blockIdx.x * 128, colBase = blockIdx.y * 128;
  int wr = (wave & 1) * 64, wc = (wave >> 1) * 64;

  f32x4 acc[4][4] = {};
  int c0 = tid, c1 = tid + 256;
  int r0 = c0 >> 2, kc0 = (c0 & 3) * 8;
  int r1 = c1 >> 2, kc1 = (c1 & 3) * 8;
  int m0 = lane & 15, kq = (lane >> 4) * 8;

  for (int k0 = 0; k0 < 256; k0 += 32){
    gld_lds16(A  + (size_t)(rowBase + r0) * 256 + k0 + kc0, (char*)As + c0 * 16);
    gld_lds16(A  + (size_t)(rowBase + r1) * 256 + k0 + kc1, (char*)As + c1 * 16);
    gld_lds16(Bt + (size_t)(colBase + r0) * 256 + k0 + kc0, (char*)Bs + c0 * 16);
    gld_lds16(Bt + (size_t)(colBase + r1) * 256 + k0 + kc1, (char*)Bs + c1 * 16);
    __syncthreads();
    bf16x8 af[4], bfr[4];
    #pragma unroll
    for (int it = 0; it < 4; ++it)
      af[it] = *(const bf16x8*)(As + (wr + it * 16 + m0) * 32 + kq);
    #pragma unroll
    for (int jt = 0; jt < 4; ++jt)
      bfr[jt] = *(const bf16x8*)(Bs + (wc + jt * 16 + m0) * 32 + kq);
    #pragma unroll
    for (int it = 0; it < 4; ++it)
      #pragma unroll
      for (int jt = 0; jt < 4; ++jt)
        acc[it][jt] = __builtin_amdgcn_mfma_f32_16x16x32_bf16(af[it], bfr[jt], acc[it][jt], 0, 0, 0);
    __syncthreads();
  }
  // epilogue: repack C/D frags (col=lane&15, row=(lane>>4)*4+reg) through LDS -> 16B stores.
  int cq = lane >> 4, cm = lane & 15;
  #pragma unroll
  for (int p = 0; p < 2; ++p){
    if ((wave >> 1) == p){
      #pragma unroll
      for (int it = 0; it < 4; ++it)
        #pragma unroll
        for (int jt = 0; jt < 4; ++jt)
          #pragma unroll
          for (int r = 0; r < 4; ++r)
            sh[(wr + it * 16 + cq * 4 + r) * 64 + jt * 16 + cm] = f2bf(acc[it][jt][r]);
    }
    __syncthreads();
    #pragma unroll
    for (int q = 0; q < 4; ++q){
      int id = tid + q * 256;            // 0..1023
      int r = id >> 3, sg = id & 7;      // row 0..127, 8-short segment 0..7
      u16x8 v = *(const u16x8*)(sh + r * 64 + sg * 8);
      *(u16x8*)(C + (size_t)(rowBase + r) * 256 + colBase + p * 64 + sg * 8) = v;
    }
    __syncthreads();
  }
}

// ------------------------- attention logits: 4 nodes/block, wave per node -------------------------
__global__ __launch_bounds__(256) void k_al4(const unsigned short* __restrict__ Hb,
                      const float* __restrict__ as_, const float* __restrict__ ad_,
                      float* als, float* ald, int n){
  int wave = threadIdx.x >> 6, lane = threadIdx.x & 63;
  int i = blockIdx.x * 4 + wave; if (i >= n) i = n - 1;
  int f = lane * 4;
  ushort4 hv = *(const ushort4*)(Hb + (size_t)i * FDIM + f);
  float4 av = *(const float4*)(as_ + f);
  float4 dv = *(const float4*)(ad_ + f);
  float h0 = bf2f(hv.x), h1 = bf2f(hv.y), h2 = bf2f(hv.z), h3 = bf2f(hv.w);
  float ps = h0*av.x + h1*av.y + h2*av.z + h3*av.w;
  float pd = h0*dv.x + h1*dv.y + h2*dv.z + h3*dv.w;
  #pragma unroll
  for (int off = 8; off >= 1; off >>= 1){       // reduce within 16-lane head groups
    ps += __shfl_down(ps, off, 16);
    pd += __shfl_down(pd, off, 16);
  }
  if ((lane & 15) == 0){
    int h = lane >> 4;
    als[i * HEADS + h] = ps; ald[i * HEADS + h] = pd;
  }
}

__global__ __launch_bounds__(256) void k_al1(const unsigned short* __restrict__ Hb,
                      const float* __restrict__ as_, const float* __restrict__ ad_,
                      float* als, float* ald, int n){
  int wave = threadIdx.x >> 6, lane = threadIdx.x & 63;
  int i = blockIdx.x * 4 + wave; if (i >= n) i = n - 1;
  int f = lane * 4;
  ushort4 hv = *(const ushort4*)(Hb + (size_t)i * FDIM + f);
  float4 av = *(const float4*)(as_ + f);
  float4 dv = *(const float4*)(ad_ + f);
  float h0 = bf2f(hv.x), h1 = bf2f(hv.y), h2 = bf2f(hv.z), h3 = bf2f(hv.w);
  float ps = h0*av.x + h1*av.y + h2*av.z + h3*av.w;
  float pd = h0*dv.x + h1*dv.y + h2*dv.z + h3*dv.w;
  #pragma unroll
  for (int off = 32; off >= 1; off >>= 1){
    ps += __shfl_down(ps, off, 64);
    pd += __shfl_down(pd, off, 64);
  }
  if (lane == 0){ als[i] = ps; ald[i] = pd; }
}

// ------------------------- layer-1 aggregation: 4 nodes/block, wave per node -------------------------
__global__ __launch_bounds__(256) void k_agg1(const unsigned short* __restrict__ Hb,
    const float* __restrict__ als, const float* __restrict__ ald,
    const int* __restrict__ rowptr, const int* __restrict__ col,
    const float* __restrict__ b, unsigned short* __restrict__ outb, int i0, int nEnd){
  __shared__ __align__(16) int   colS[4][MAXD];
  __shared__ __align__(16) float wS[4][MAXD][4];
  int wave = threadIdx.x >> 6, t = threadIdx.x & 63;
  int i = i0 + blockIdx.x * 4 + wave; if (i >= nEnd) i = nEnd - 1;
  int start = rowptr[i];
  int deg = rowptr[i + 1] - start;
  float4 adv = *(const float4*)(ald + (size_t)i * 4);
  bool staged = (deg <= MAXD);

  float4 ls = make_float4(0.f, 0.f, 0.f, 0.f);
  if (staged){
    for (int j = t; j < deg; j += 64){
      int s = col[start + j];
      colS[wave][j] = s;
      float4 a = *(const float4*)(als + (size_t)s * 4);
      float4 w = make_float4(__expf(leaky(a.x + adv.x)), __expf(leaky(a.y + adv.y)),
                             __expf(leaky(a.z + adv.z)), __expf(leaky(a.w + adv.w)));
      *(float4*)(&wS[wave][j][0]) = w;
      ls.x += w.x; ls.y += w.y; ls.z += w.z; ls.w += w.w;
    }
  } else {
    for (int j = t; j < deg; j += 64){
      int s = col[start + j];
      float4 a = *(const float4*)(als + (size_t)s * 4);
      ls.x += __expf(leaky(a.x + adv.x)); ls.y += __expf(leaky(a.y + adv.y));
      ls.z += __expf(leaky(a.z + adv.z)); ls.w += __expf(leaky(a.w + adv.w));
    }
  }
  #pragma unroll
  for (int off = 32; off >= 1; off >>= 1) ls = make_float4(
      ls.x + __shfl_down(ls.x, off, 64), ls.y + __shfl_down(ls.y, off, 64),
      ls.z + __shfl_down(ls.z, off, 64), ls.w + __shfl_down(ls.w, off, 64));
  float4 d4 = bcast4(ls);
  __syncthreads();

  int e2 = t >> 5, l32 = t & 31;
  int h = l32 >> 3, f = l32 * 8;
  float inv = 1.f / (comp4(d4, h) + 1e-16f);
  const unsigned short* Hrow = Hb + f;
  float a0[8] = {0,0,0,0,0,0,0,0}, a1[8] = {0,0,0,0,0,0,0,0};
  if (staged){
    int j = 0;
    for (; j + 3 < deg; j += 4){
      int j0 = j + e2, j1 = j + 2 + e2;
      int s0 = colS[wave][j0], s1 = colS[wave][j1];
      float w0 = wS[wave][j0][h], w1 = wS[wave][j1][h];
      u16x8 h0 = *(const u16x8*)(Hrow + (size_t)s0 * FDIM);
      u16x8 h1 = *(const u16x8*)(Hrow + (size_t)s1 * FDIM);
      #pragma unroll
      for (int k = 0; k < 8; ++k){ a0[k] += bf2f(h0[k]) * w0; a1[k] += bf2f(h1[k]) * w1; }
    }
    for (; j < deg; j += 2){
      int jj = j + e2;
      if (jj < deg){
        int s = colS[wave][jj]; float w = wS[wave][jj][h];
        u16x8 hh = *(const u16x8*)(Hrow + (size_t)s * FDIM);
        #pragma unroll
        for (int k = 0; k < 8; ++k) a0[k] += bf2f(hh[k]) * w;
      }
    }
  } else {
    float adh = comp4(adv, h);
    for (int j = e2; j < deg; j += 2){
      int s = col[start + j];
      float w = __expf(leaky(als[(size_t)s * 4 + h] + adh));
      u16x8 hh = *(const u16x8*)(Hrow + (size_t)s * FDIM);
      #pragma unroll
      for (int k = 0; k < 8; ++k) a0[k] += bf2f(hh[k]) * w;
    }
  }
  float r[8];
  #pragma unroll
  for (int k = 0; k < 8; ++k){
    r[k] = a0[k] + a1[k];
    r[k] += __shfl_down(r[k], 32, 64);
  }
  if (t < 32){
    float4 bA = *(const float4*)(b + f);
    float4 bB = *(const float4*)(b + f + 4);
    float bb[8] = {bA.x, bA.y, bA.z, bA.w, bB.x, bB.y, bB.z, bB.w};
    u16x8 o;
    #pragma unroll
    for (int k = 0; k < 8; ++k){
      float v = r[k] * inv + bb[k];
      v = (v > 0.f) ? v : (__expf(v) - 1.f);    // ELU
      o[k] = f2bf(v);
    }
    *(u16x8*)(outb + (size_t)i * FDIM + f) = o;
  }
}

// ------------------------- layer-2 aggregation: 4 nodes/block, wave per node, fp32 out -------------------------
__global__ __launch_bounds__(256) void k_agg2(const unsigned short* __restrict__ Hb,
    const float* __restrict__ als, const float* __restrict__ ald,
    const int* __restrict__ rowptr, const int* __restrict__ col,
    const float* __restrict__ b, float* __restrict__ out, int i0, int nEnd){
  __shared__ __align__(16) int   colS[4][MAXD];
  __shared__ __align__(16) float wS[4][MAXD];
  int wave = threadIdx.x >> 6, t = threadIdx.x & 63;
  int i = i0 + blockIdx.x * 4 + wave; if (i >= nEnd) i = nEnd - 1;
  int start = rowptr[i];
  int deg = rowptr[i + 1] - start;
  float adv = ald[i];
  bool staged = (deg <= MAXD);

  float ls = 0.f;
  if (staged){
    for (int j = t; j < deg; j += 64){
      int s = col[start + j];
      colS[wave][j] = s;
      float w = __expf(leaky(als[s] + adv));
      wS[wave][j] = w;
      ls += w;
    }
  } else {
    for (int j = t; j < deg; j += 64) ls += __expf(leaky(als[col[start + j]] + adv));
  }
  #pragma unroll
  for (int off = 32; off >= 1; off >>= 1) ls += __shfl_down(ls, off, 64);
  float inv = 1.f / (__shfl(ls, 0, 64) + 1e-16f);
  __syncthreads();

  int e2 = t >> 5, l32 = t & 31;
  int f = l32 * 8;
  const unsigned short* Hrow = Hb + f;
  float a0[8] = {0,0,0,0,0,0,0,0}, a1[8] = {0,0,0,0,0,0,0,0};
  if (staged){
    int j = 0;
    for (; j + 3 < deg; j += 4){
      int j0 = j + e2, j1 = j + 2 + e2;
      int s0 = colS[wave][j0], s1 = colS[wave][j1];
      float w0 = wS[wave][j0], w1 = wS[wave][j1];
      u16x8 h0 = *(const u16x8*)(Hrow + (size_t)s0 * FDIM);
      u16x8 h1 = *(const u16x8*)(Hrow + (size_t)s1 * FDIM);
      #pragma unroll
      for (int k = 0; k < 8; ++k){ a0[k] += bf2f(h0[k]) * w0; a1[k] += bf2f(h1[k]) * w1; }
    }
    for (; j < deg; j += 2){
      int jj = j + e2;
      if (jj < deg){
        int s = colS[wave][jj]; float w = wS[wave][jj];
        u16x8 hh = *(const u16x8*)(Hrow + (size_t)s * FDIM);
        #pragma unroll
        for (int k = 0; k < 8; ++k) a0[k] += bf2f(hh[k]) * w;
      }
    }
  } else {
    for (int j = e2; j < deg; j += 2){
      int s = col[start + j];
      float w = __expf(leaky(als[s] + adv));
      u16x8 hh = *(const u16x8*)(Hrow + (size_t)s * FDIM);
      #pragma unroll
      for (int k = 0; k < 8; ++k) a0[k] += bf2f(hh[k]) * w;
    }
  }
  float r[8];
  #pragma unroll
  for (int k = 0; k < 8; ++k){
    r[k] = a0[k] + a1[k];
    r[k] += __shfl_down(r[k], 32, 64);
  }
  if (t < 32){
    float4 bA = *(const float4*)(b + f);
    float4 bB = *(const float4*)(b + f + 4);
    float4 oA = make_float4(r[0]*inv + bA.x, r[1]*inv + bA.y, r[2]*inv + bA.z, r[3]*inv + bA.w);
    float4 oB = make_float4(r[4]*inv + bB.x, r[5]*inv + bB.y, r[6]*inv + bB.z, r[7]*inv + bB.w);
    *(float4*)(out + (size_t)i * FDIM + f) = oA;
    *(float4*)(out + (size_t)i * FDIM + f + 4) = oB;
  }
}

// ------------------------- launch -------------------------
extern "C" void kernel_launch(void* const* d_in, const int* in_sizes, int n_in,
                              void* d_out, int out_size, void* d_ws, size_t ws_size,
                              hipStream_t stream){
  const float* x   = (const float*)d_in[0];
  const int*   ei  = (const int*)d_in[1];
  const float* W1  = (const float*)d_in[2];
  const float* as1 = (const float*)d_in[3];
  const float* ad1 = (const float*)d_in[4];
  const float* b1  = (const float*)d_in[5];
  const float* W2  = (const float*)d_in[6];
  const float* as2 = (const float*)d_in[7];
  const float* ad2 = (const float*)d_in[8];
  const float* b2  = (const float*)d_in[9];
  float* out = (float*)d_out;

  int n = in_sizes[0] / IN_DIM;     // 50000
  int E = in_sizes[1] / 2;          // 800000
  int Mpad = (n + 127) & ~127;      // 50048
  const int* srcIdx = ei;
  const int* dstIdx = ei + E;

  char* ws = (char*)d_ws;
  size_t off = 0;
  auto alloc = [&](size_t bytes) -> void* {
    void* p = ws + off; off += (bytes + 255) & ~(size_t)255; return p;
  };
  unsigned short* bufA = (unsigned short*)alloc((size_t)Mpad * FDIM * 2);  // out1b
  unsigned short* bufB = (unsigned short*)alloc((size_t)Mpad * FDIM * 2);  // H1b, then H2b
  unsigned short* W1t  = (unsigned short*)alloc(256 * 256 * 2);
  unsigned short* W2t  = (unsigned short*)alloc(256 * 256 * 2);
  // zero block: deg | fill (single memset)
  int*   zeros    = (int*)alloc((size_t)n * 2 * 4);
  int*   deg      = zeros;
  int*   fill     = zeros + n;
  int*   tmp      = (int*)alloc((size_t)n * 4);
  int*   rowptr   = (int*)alloc((size_t)(n + 1) * 4);
  int*   partials = (int*)alloc(1024 * 4);
  int*   col      = (int*)alloc((size_t)(E + n) * 4);
  float* als1     = (float*)alloc((size_t)n * HEADS * 4);
  float* ald1     = (float*)alloc((size_t)n * HEADS * 4);
  float* als2     = (float*)alloc((size_t)n * 4);
  float* ald2     = (float*)alloc((size_t)n * 4);
  (void)ws_size;

  int nb = (n + 255) / 256;
  hipMemsetAsync(zeros, 0, (size_t)n * 2 * 4, stream);

  // W transposes (LDS, coalesced) + degree histogram
  int histBlocks = (E + 255) / 256;
  k_wthist<<<32 + histBlocks, 256, 0, stream>>>(W1, W1t, W2, W2t, dstIdx, deg, E);

  // CSR build
  k_scanA<<<nb, 256, 0, stream>>>(deg, tmp, partials, n);
  k_scanC<<<nb, 256, 0, stream>>>(tmp, deg, partials, rowptr, n, nb);
  k_fill<<<(E + n + 255) / 256, 256, 0, stream>>>(srcIdx, dstIdx, rowptr, fill, col, E, n);

  dim3 gg(Mpad / 128, FDIM / 128);
  int ga = (n + 3) / 4;
  int nA = 25000;                       // split point (multiple of 4)
  int gaA = nA / 4, gaB = (n - nA + 3) / 4;
  // layer 1 (x cast fused into GEMM1 A-staging)
  k_gemm1<<<gg, 256, 0, stream>>>(x, W1t, bufB, n);                          // H1b
  k_al4<<<ga, 256, 0, stream>>>(bufB, as1, ad1, als1, ald1, n);
  k_agg1<<<gaA, 256, 0, stream>>>(bufB, als1, ald1, rowptr, col, b1, bufA, 0, nA);
  k_agg1<<<gaB, 256, 0, stream>>>(bufB, als1, ald1, rowptr, col, b1, bufA, nA, n);
  // layer 2
  k_gemm<<<gg, 256, 0, stream>>>(bufA, W2t, bufB);                           // H2b
  k_al1<<<ga, 256, 0, stream>>>(bufB, as2, ad2, als2, ald2, n);
  k_agg2<<<gaA, 256, 0, stream>>>(bufB, als2, ald2, rowptr, col, b2, out, 0, nA);
  k_agg2<<<gaB, 256, 0, stream>>>(bufB, als2, ald2, rowptr, col, b2, out, nA, n);
}

// Round 10
// 376.611 us; speedup vs baseline: 1.0634x; 1.0634x over previous
//
#include <hip/hip_runtime.h>
#include <math.h>

#define IN_DIM 256
#define FDIM 256      // HEADS*HID == OUT == 256
#define HEADS 4
#define NEG 0.2f
#define MAXD 96       // per-node staged edge cap; in-deg ~ Poisson(16)+1, P(>96) ~ 0
#define CPB 2048      // edges per fill-chunk (x8 teams)

typedef __attribute__((ext_vector_type(8))) short bf16x8;
typedef __attribute__((ext_vector_type(8))) unsigned short u16x8;
typedef __attribute__((ext_vector_type(4))) float f32x4;

__device__ __forceinline__ float leaky(float x){ return x > 0.f ? x : NEG * x; }

__device__ __forceinline__ unsigned short f2bf(float f){
  unsigned int u = __float_as_uint(f);
  unsigned int r = u + 0x7fffu + ((u >> 16) & 1u);   // round-to-nearest-even
  return (unsigned short)(r >> 16);
}
__device__ __forceinline__ float bf2f(unsigned short s){
  return __uint_as_float(((unsigned int)s) << 16);
}

__device__ __forceinline__ float4 bcast4(float4 v){
  return make_float4(__shfl(v.x,0,64), __shfl(v.y,0,64), __shfl(v.z,0,64), __shfl(v.w,0,64));
}
__device__ __forceinline__ float comp4(float4 v, int h){
  return h==0 ? v.x : h==1 ? v.y : h==2 ? v.z : v.w;
}

__device__ __forceinline__ void gld_lds16(const void* g, void* l){
  __builtin_amdgcn_global_load_lds((const __attribute__((address_space(1))) unsigned int*)g,
                                   (__attribute__((address_space(3))) unsigned int*)l, 16, 0, 0);
}

// ------------------------- W1/W2 transpose-cast (LDS, coalesced) -------------------------
__global__ void k_wt(const float* __restrict__ W1, unsigned short* __restrict__ W1t,
                     const float* __restrict__ W2, unsigned short* __restrict__ W2t){
  __shared__ float tile[64][65];
  int b = blockIdx.x;
  const float* W = (b < 16) ? W1 : W2;
  unsigned short* Wt = (b < 16) ? W1t : W2t;
  int bb = b & 15;
  int tk = (bb >> 2) * 64, tn = (bb & 3) * 64;   // 4x4 grid of 64x64 tiles
  int t = threadIdx.x;
  int cr = t >> 6, cc = t & 63;                  // wave-row, lane-col
  #pragma unroll
  for (int r = 0; r < 16; ++r){
    int k = r * 4 + cr;
    tile[k][cc] = W[(size_t)(tk + k) * 256 + tn + cc];   // coalesced 256B/wave
  }
  __syncthreads();
  #pragma unroll
  for (int r = 0; r < 16; ++r){
    int nn = r * 4 + cr;
    Wt[(size_t)(tn + nn) * 256 + tk + cc] = f2bf(tile[cc][nn]);  // pad(65) -> conflict-free
  }
}

// ------------------------- fused: GEMM1 (fp32 A cast-staged) + degree histogram -------------------------
// gemm blocks [0, 2*nbx) run layer-1 GEMM; trailing blocks stream dst and histogram degrees.
// Independent work: hist atomics' latency hides under concurrent MFMA waves.
__global__ __launch_bounds__(256) void k_g1h(const float* __restrict__ X,
                                             const unsigned short* __restrict__ Bt,
                                             unsigned short* __restrict__ C, int n, int nbx,
                                             const int* __restrict__ dst, int* __restrict__ deg, int E){
  int b = blockIdx.x;
  int gemmB = 2 * nbx;
  if (b >= gemmB){
    int e = (b - gemmB) * 256 + threadIdx.x;
    if (e < E) atomicAdd(&deg[dst[e]], 1);
    return;
  }
  __shared__ __align__(16) unsigned short sh[8192];   // As = sh[0:4096], Bs = sh[4096:8192]
  unsigned short* As = sh;
  unsigned short* Bs = sh + 4096;
  int tid = threadIdx.x;
  int lane = tid & 63, wave = tid >> 6;
  int rowBase = (b % nbx) * 128, colBase = (b / nbx) * 128;
  int wr = (wave & 1) * 64, wc = (wave >> 1) * 64;

  f32x4 acc[4][4] = {};
  int c0 = tid, c1 = tid + 256;
  int r0 = c0 >> 2, kc0 = (c0 & 3) * 8;
  int r1 = c1 >> 2, kc1 = (c1 & 3) * 8;
  int m0 = lane & 15, kq = (lane >> 4) * 8;
  int ra = rowBase + r0; if (ra >= n) ra = n - 1;   // clamp: padded rows feed unused C rows
  int rb = rowBase + r1; if (rb >= n) rb = n - 1;

  for (int k0 = 0; k0 < 256; k0 += 32){
    float4 va0 = *(const float4*)(X + (size_t)ra * 256 + k0 + kc0);
    float4 va1 = *(const float4*)(X + (size_t)ra * 256 + k0 + kc0 + 4);
    float4 vb0 = *(const float4*)(X + (size_t)rb * 256 + k0 + kc1);
    float4 vb1 = *(const float4*)(X + (size_t)rb * 256 + k0 + kc1 + 4);
    u16x8 sa, sb;
    sa[0]=f2bf(va0.x); sa[1]=f2bf(va0.y); sa[2]=f2bf(va0.z); sa[3]=f2bf(va0.w);
    sa[4]=f2bf(va1.x); sa[5]=f2bf(va1.y); sa[6]=f2bf(va1.z); sa[7]=f2bf(va1.w);
    sb[0]=f2bf(vb0.x); sb[1]=f2bf(vb0.y); sb[2]=f2bf(vb0.z); sb[3]=f2bf(vb0.w);
    sb[4]=f2bf(vb1.x); sb[5]=f2bf(vb1.y); sb[6]=f2bf(vb1.z); sb[7]=f2bf(vb1.w);
    *(u16x8*)(As + c0 * 8) = sa;
    *(u16x8*)(As + c1 * 8) = sb;
    gld_lds16(Bt + (size_t)(colBase + r0) * 256 + k0 + kc0, (char*)Bs + c0 * 16);
    gld_lds16(Bt + (size_t)(colBase + r1) * 256 + k0 + kc1, (char*)Bs + c1 * 16);
    __syncthreads();
    bf16x8 af[4], bfr[4];
    #pragma unroll
    for (int it = 0; it < 4; ++it)
      af[it] = *(const bf16x8*)(As + (wr + it * 16 + m0) * 32 + kq);
    #pragma unroll
    for (int jt = 0; jt < 4; ++jt)
      bfr[jt] = *(const bf16x8*)(Bs + (wc + jt * 16 + m0) * 32 + kq);
    #pragma unroll
    for (int it = 0; it < 4; ++it)
      #pragma unroll
      for (int jt = 0; jt < 4; ++jt)
        acc[it][jt] = __builtin_amdgcn_mfma_f32_16x16x32_bf16(af[it], bfr[jt], acc[it][jt], 0, 0, 0);
    __syncthreads();
  }
  int cq = lane >> 4, cm = lane & 15;
  #pragma unroll
  for (int p = 0; p < 2; ++p){
    if ((wave >> 1) == p){
      #pragma unroll
      for (int it = 0; it < 4; ++it)
        #pragma unroll
        for (int jt = 0; jt < 4; ++jt)
          #pragma unroll
          for (int r = 0; r < 4; ++r)
            sh[(wr + it * 16 + cq * 4 + r) * 64 + jt * 16 + cm] = f2bf(acc[it][jt][r]);
    }
    __syncthreads();
    #pragma unroll
    for (int q = 0; q < 4; ++q){
      int id = tid + q * 256;
      int r = id >> 3, sg = id & 7;
      u16x8 v = *(const u16x8*)(sh + r * 64 + sg * 8);
      *(u16x8*)(C + (size_t)(rowBase + r) * 256 + colBase + p * 64 + sg * 8) = v;
    }
    __syncthreads();
  }
}

// ------------------------- CSR scans -------------------------
__global__ void k_scanA(const int* __restrict__ deg, int* tmp, int* partials, int n){
  __shared__ int sm[256];
  int i = blockIdx.x * 256 + threadIdx.x;
  int v = (i < n) ? deg[i] + 1 : 0;     // +1: self loop
  sm[threadIdx.x] = v; __syncthreads();
  for (int off = 1; off < 256; off <<= 1){
    int x = (threadIdx.x >= off) ? sm[threadIdx.x - off] : 0;
    __syncthreads();
    sm[threadIdx.x] += x;
    __syncthreads();
  }
  if (i < n) tmp[i] = sm[threadIdx.x];            // inclusive within block
  if (threadIdx.x == 255) partials[blockIdx.x] = sm[255];
}

__global__ void k_scanC(const int* __restrict__ tmp, const int* __restrict__ deg,
                        const int* __restrict__ partials, int* rowptr, int n, int nb){
  __shared__ int ws[4];
  int bid = blockIdx.x, t = threadIdx.x;
  int lane = t & 63, w = t >> 6;
  int v = (t < bid && t < nb) ? partials[t] : 0;
  #pragma unroll
  for (int off = 32; off >= 1; off >>= 1) v += __shfl_down(v, off, 64);
  if (lane == 0) ws[w] = v;
  __syncthreads();
  int prefix = ws[0] + ws[1] + ws[2] + ws[3];
  int i = bid * 256 + t;
  if (i < n){
    int incl = tmp[i] + prefix;
    rowptr[i] = incl - (deg[i] + 1);
    if (i == n - 1) rowptr[n] = incl;             // total = E + n
  }
}

// ------------------------- fused: XCD-partitioned fill + layer-1 attention logits -------------------------
// fill blocks: team = b&7 -> XCD via round-robin; team owns dst range [team*span, ...).
// Writes to col land in the team's contiguous region (XCD-L2-resident) -> no cross-XCD line ping-pong.
// Trailing blocks compute al4 (needs H1b, produced by the previous kernel).
__global__ __launch_bounds__(256) void k_fillal4(const int* __restrict__ src, const int* __restrict__ dst,
    const int* __restrict__ rowptr, int* fill, int* col, int E, int n, int fillB,
    const unsigned short* __restrict__ Hb, const float* __restrict__ as_, const float* __restrict__ ad_,
    float* als, float* ald){
  int b = blockIdx.x;
  if (b < fillB){
    int team = b & 7, chunk = b >> 3;
    int span = (n + 7) >> 3;
    int lo = team * span, hi = lo + span; if (hi > n) hi = n;
    int base = chunk * CPB + threadIdx.x;
    #pragma unroll
    for (int it = 0; it < CPB / 256; ++it){
      int e = base + it * 256;
      if (e < E + n){
        int d = (e < E) ? dst[e] : e - E;
        if (d >= lo && d < hi){
          int s = (e < E) ? src[e] : d;
          int pos = atomicAdd(&fill[d], 1);
          col[rowptr[d] + pos] = s;
        }
      }
    }
    return;
  }
  int wave = threadIdx.x >> 6, lane = threadIdx.x & 63;
  int i = (b - fillB) * 4 + wave; if (i >= n) i = n - 1;
  int f = lane * 4;
  ushort4 hv = *(const ushort4*)(Hb + (size_t)i * FDIM + f);
  float4 av = *(const float4*)(as_ + f);
  float4 dv = *(const float4*)(ad_ + f);
  float h0 = bf2f(hv.x), h1 = bf2f(hv.y), h2 = bf2f(hv.z), h3 = bf2f(hv.w);
  float ps = h0*av.x + h1*av.y + h2*av.z + h3*av.w;
  float pd = h0*dv.x + h1*dv.y + h2*dv.z + h3*dv.w;
  #pragma unroll
  for (int off = 8; off >= 1; off >>= 1){       // reduce within 16-lane head groups
    ps += __shfl_down(ps, off, 16);
    pd += __shfl_down(pd, off, 16);
  }
  if ((lane & 15) == 0){
    int h = lane >> 4;
    als[i * HEADS + h] = ps; ald[i * HEADS + h] = pd;
  }
}

// ------------------------- bf16 MFMA GEMM: C[M,256] = A[M,256] @ Bt[256,256]^T -------------------------
__global__ __launch_bounds__(256) void k_gemm(const unsigned short* __restrict__ A,
                                              const unsigned short* __restrict__ Bt,
                                              unsigned short* __restrict__ C){
  __shared__ __align__(16) unsigned short sh[8192];
  unsigned short* As = sh;
  unsigned short* Bs = sh + 4096;
  int tid = threadIdx.x;
  int lane = tid & 63, wave = tid >> 6;
  int rowBase = blockIdx.x * 128, colBase = blockIdx.y * 128;
  int wr = (wave & 1) * 64, wc = (wave >> 1) * 64;

  f32x4 acc[4][4] = {};
  int c0 = tid, c1 = tid + 256;
  int r0 = c0 >> 2, kc0 = (c0 & 3) * 8;
  int r1 = c1 >> 2, kc1 = (c1 & 3) * 8;
  int m0 = lane & 15, kq = (lane >> 4) * 8;

  for (int k0 = 0; k0 < 256; k0 += 32){
    gld_lds16(A  + (size_t)(rowBase + r0) * 256 + k0 + kc0, (char*)As + c0 * 16);
    gld_lds16(A  + (size_t)(rowBase + r1) * 256 + k0 + kc1, (char*)As + c1 * 16);
    gld_lds16(Bt + (size_t)(colBase + r0) * 256 + k0 + kc0, (char*)Bs + c0 * 16);
    gld_lds16(Bt + (size_t)(colBase + r1) * 256 + k0 + kc1, (char*)Bs + c1 * 16);
    __syncthreads();
    bf16x8 af[4], bfr[4];
    #pragma unroll
    for (int it = 0; it < 4; ++it)
      af[it] = *(const bf16x8*)(As + (wr + it * 16 + m0) * 32 + kq);
    #pragma unroll
    for (int jt = 0; jt < 4; ++jt)
      bfr[jt] = *(const bf16x8*)(Bs + (wc + jt * 16 + m0) * 32 + kq);
    #pragma unroll
    for (int it = 0; it < 4; ++it)
      #pragma unroll
      for (int jt = 0; jt < 4; ++jt)
        acc[it][jt] = __builtin_amdgcn_mfma_f32_16x16x32_bf16(af[it], bfr[jt], acc[it][jt], 0, 0, 0);
    __syncthreads();
  }
  int cq = lane >> 4, cm = lane & 15;
  #pragma unroll
  for (int p = 0; p < 2; ++p){
    if ((wave >> 1) == p){
      #pragma unroll
      for (int it = 0; it < 4; ++it)
        #pragma unroll
        for (int jt = 0; jt < 4; ++jt)
          #pragma unroll
          for (int r = 0; r < 4; ++r)
            sh[(wr + it * 16 + cq * 4 + r) * 64 + jt * 16 + cm] = f2bf(acc[it][jt][r]);
    }
    __syncthreads();
    #pragma unroll
    for (int q = 0; q < 4; ++q){
      int id = tid + q * 256;
      int r = id >> 3, sg = id & 7;
      u16x8 v = *(const u16x8*)(sh + r * 64 + sg * 8);
      *(u16x8*)(C + (size_t)(rowBase + r) * 256 + colBase + p * 64 + sg * 8) = v;
    }
    __syncthreads();
  }
}

// ------------------------- layer-2 attention logits -------------------------
__global__ __launch_bounds__(256) void k_al1(const unsigned short* __restrict__ Hb,
                      const float* __restrict__ as_, const float* __restrict__ ad_,
                      float* als, float* ald, int n){
  int wave = threadIdx.x >> 6, lane = threadIdx.x & 63;
  int i = blockIdx.x * 4 + wave; if (i >= n) i = n - 1;
  int f = lane * 4;
  ushort4 hv = *(const ushort4*)(Hb + (size_t)i * FDIM + f);
  float4 av = *(const float4*)(as_ + f);
  float4 dv = *(const float4*)(ad_ + f);
  float h0 = bf2f(hv.x), h1 = bf2f(hv.y), h2 = bf2f(hv.z), h3 = bf2f(hv.w);
  float ps = h0*av.x + h1*av.y + h2*av.z + h3*av.w;
  float pd = h0*dv.x + h1*dv.y + h2*dv.z + h3*dv.w;
  #pragma unroll
  for (int off = 32; off >= 1; off >>= 1){
    ps += __shfl_down(ps, off, 64);
    pd += __shfl_down(pd, off, 64);
  }
  if (lane == 0){ als[i] = ps; ald[i] = pd; }
}

// ------------------------- layer-1 aggregation: 4 nodes/block, wave per node -------------------------
__global__ __launch_bounds__(256) void k_agg1(const unsigned short* __restrict__ Hb,
    const float* __restrict__ als, const float* __restrict__ ald,
    const int* __restrict__ rowptr, const int* __restrict__ col,
    const float* __restrict__ b, unsigned short* __restrict__ outb, int i0, int nEnd){
  __shared__ __align__(16) int   colS[4][MAXD];
  __shared__ __align__(16) float wS[4][MAXD][4];
  int wave = threadIdx.x >> 6, t = threadIdx.x & 63;
  int i = i0 + blockIdx.x * 4 + wave; if (i >= nEnd) i = nEnd - 1;
  int start = rowptr[i];
  int deg = rowptr[i + 1] - start;
  float4 adv = *(const float4*)(ald + (size_t)i * 4);
  bool staged = (deg <= MAXD);

  float4 ls = make_float4(0.f, 0.f, 0.f, 0.f);
  if (staged){
    for (int j = t; j < deg; j += 64){
      int s = col[start + j];
      colS[wave][j] = s;
      float4 a = *(const float4*)(als + (size_t)s * 4);
      float4 w = make_float4(__expf(leaky(a.x + adv.x)), __expf(leaky(a.y + adv.y)),
                             __expf(leaky(a.z + adv.z)), __expf(leaky(a.w + adv.w)));
      *(float4*)(&wS[wave][j][0]) = w;
      ls.x += w.x; ls.y += w.y; ls.z += w.z; ls.w += w.w;
    }
  } else {
    for (int j = t; j < deg; j += 64){
      int s = col[start + j];
      float4 a = *(const float4*)(als + (size_t)s * 4);
      ls.x += __expf(leaky(a.x + adv.x)); ls.y += __expf(leaky(a.y + adv.y));
      ls.z += __expf(leaky(a.z + adv.z)); ls.w += __expf(leaky(a.w + adv.w));
    }
  }
  #pragma unroll
  for (int off = 32; off >= 1; off >>= 1) ls = make_float4(
      ls.x + __shfl_down(ls.x, off, 64), ls.y + __shfl_down(ls.y, off, 64),
      ls.z + __shfl_down(ls.z, off, 64), ls.w + __shfl_down(ls.w, off, 64));
  float4 d4 = bcast4(ls);
  __syncthreads();

  int e2 = t >> 5, l32 = t & 31;
  int h = l32 >> 3, f = l32 * 8;
  float inv = 1.f / (comp4(d4, h) + 1e-16f);
  const unsigned short* Hrow = Hb + f;
  float a0[8] = {0,0,0,0,0,0,0,0}, a1[8] = {0,0,0,0,0,0,0,0};
  if (staged){
    int j = 0;
    for (; j + 3 < deg; j += 4){
      int j0 = j + e2, j1 = j + 2 + e2;
      int s0 = colS[wave][j0], s1 = colS[wave][j1];
      float w0 = wS[wave][j0][h], w1 = wS[wave][j1][h];
      u16x8 h0 = *(const u16x8*)(Hrow + (size_t)s0 * FDIM);
      u16x8 h1 = *(const u16x8*)(Hrow + (size_t)s1 * FDIM);
      #pragma unroll
      for (int k = 0; k < 8; ++k){ a0[k] += bf2f(h0[k]) * w0; a1[k] += bf2f(h1[k]) * w1; }
    }
    for (; j < deg; j += 2){
      int jj = j + e2;
      if (jj < deg){
        int s = colS[wave][jj]; float w = wS[wave][jj][h];
        u16x8 hh = *(const u16x8*)(Hrow + (size_t)s * FDIM);
        #pragma unroll
        for (int k = 0; k < 8; ++k) a0[k] += bf2f(hh[k]) * w;
      }
    }
  } else {
    float adh = comp4(adv, h);
    for (int j = e2; j < deg; j += 2){
      int s = col[start + j];
      float w = __expf(leaky(als[(size_t)s * 4 + h] + adh));
      u16x8 hh = *(const u16x8*)(Hrow + (size_t)s * FDIM);
      #pragma unroll
      for (int k = 0; k < 8; ++k) a0[k] += bf2f(hh[k]) * w;
    }
  }
  float r[8];
  #pragma unroll
  for (int k = 0; k < 8; ++k){
    r[k] = a0[k] + a1[k];
    r[k] += __shfl_down(r[k], 32, 64);
  }
  if (t < 32){
    float4 bA = *(const float4*)(b + f);
    float4 bB = *(const float4*)(b + f + 4);
    float bb[8] = {bA.x, bA.y, bA.z, bA.w, bB.x, bB.y, bB.z, bB.w};
    u16x8 o;
    #pragma unroll
    for (int k = 0; k < 8; ++k){
      float v = r[k] * inv + bb[k];
      v = (v > 0.f) ? v : (__expf(v) - 1.f);    // ELU
      o[k] = f2bf(v);
    }
    *(u16x8*)(outb + (size_t)i * FDIM + f) = o;
  }
}

// ------------------------- layer-2 aggregation: 4 nodes/block, wave per node, fp32 out -------------------------
__global__ __launch_bounds__(256) void k_agg2(const unsigned short* __restrict__ Hb,
    const float* __restrict__ als, const float* __restrict__ ald,
    const int* __restrict__ rowptr, const int* __restrict__ col,
    const float* __restrict__ b, float* __restrict__ out, int i0, int nEnd){
  __shared__ __align__(16) int   colS[4][MAXD];
  __shared__ __align__(16) float wS[4][MAXD];
  int wave = threadIdx.x >> 6, t = threadIdx.x & 63;
  int i = i0 + blockIdx.x * 4 + wave; if (i >= nEnd) i = nEnd - 1;
  int start = rowptr[i];
  int deg = rowptr[i + 1] - start;
  float adv = ald[i];
  bool staged = (deg <= MAXD);

  float ls = 0.f;
  if (staged){
    for (int j = t; j < deg; j += 64){
      int s = col[start + j];
      colS[wave][j] = s;
      float w = __expf(leaky(als[s] + adv));
      wS[wave][j] = w;
      ls += w;
    }
  } else {
    for (int j = t; j < deg; j += 64) ls += __expf(leaky(als[col[start + j]] + adv));
  }
  #pragma unroll
  for (int off = 32; off >= 1; off >>= 1) ls += __shfl_down(ls, off, 64);
  float inv = 1.f / (__shfl(ls, 0, 64) + 1e-16f);
  __syncthreads();

  int e2 = t >> 5, l32 = t & 31;
  int f = l32 * 8;
  const unsigned short* Hrow = Hb + f;
  float a0[8] = {0,0,0,0,0,0,0,0}, a1[8] = {0,0,0,0,0,0,0,0};
  if (staged){
    int j = 0;
    for (; j + 3 < deg; j += 4){
      int j0 = j + e2, j1 = j + 2 + e2;
      int s0 = colS[wave][j0], s1 = colS[wave][j1];
      float w0 = wS[wave][j0], w1 = wS[wave][j1];
      u16x8 h0 = *(const u16x8*)(Hrow + (size_t)s0 * FDIM);
      u16x8 h1 = *(const u16x8*)(Hrow + (size_t)s1 * FDIM);
      #pragma unroll
      for (int k = 0; k < 8; ++k){ a0[k] += bf2f(h0[k]) * w0; a1[k] += bf2f(h1[k]) * w1; }
    }
    for (; j < deg; j += 2){
      int jj = j + e2;
      if (jj < deg){
        int s = colS[wave][jj]; float w = wS[wave][jj];
        u16x8 hh = *(const u16x8*)(Hrow + (size_t)s * FDIM);
        #pragma unroll
        for (int k = 0; k < 8; ++k) a0[k] += bf2f(hh[k]) * w;
      }
    }
  } else {
    for (int j = e2; j < deg; j += 2){
      int s = col[start + j];
      float w = __expf(leaky(als[s] + adv));
      u16x8 hh = *(const u16x8*)(Hrow + (size_t)s * FDIM);
      #pragma unroll
      for (int k = 0; k < 8; ++k) a0[k] += bf2f(hh[k]) * w;
    }
  }
  float r[8];
  #pragma unroll
  for (int k = 0; k < 8; ++k){
    r[k] = a0[k] + a1[k];
    r[k] += __shfl_down(r[k], 32, 64);
  }
  if (t < 32){
    float4 bA = *(const float4*)(b + f);
    float4 bB = *(const float4*)(b + f + 4);
    float4 oA = make_float4(r[0]*inv + bA.x, r[1]*inv + bA.y, r[2]*inv + bA.z, r[3]*inv + bA.w);
    float4 oB = make_float4(r[4]*inv + bB.x, r[5]*inv + bB.y, r[6]*inv + bB.z, r[7]*inv + bB.w);
    *(float4*)(out + (size_t)i * FDIM + f) = oA;
    *(float4*)(out + (size_t)i * FDIM + f + 4) = oB;
  }
}

// ------------------------- launch -------------------------
extern "C" void kernel_launch(void* const* d_in, const int* in_sizes, int n_in,
                              void* d_out, int out_size, void* d_ws, size_t ws_size,
                              hipStream_t stream){
  const float* x   = (const float*)d_in[0];
  const int*   ei  = (const int*)d_in[1];
  const float* W1  = (const float*)d_in[2];
  const float* as1 = (const float*)d_in[3];
  const float* ad1 = (const float*)d_in[4];
  const float* b1  = (const float*)d_in[5];
  const float* W2  = (const float*)d_in[6];
  const float* as2 = (const float*)d_in[7];
  const float* ad2 = (const float*)d_in[8];
  const float* b2  = (const float*)d_in[9];
  float* out = (float*)d_out;

  int n = in_sizes[0] / IN_DIM;     // 50000
  int E = in_sizes[1] / 2;          // 800000
  int Mpad = (n + 127) & ~127;      // 50048
  const int* srcIdx = ei;
  const int* dstIdx = ei + E;

  char* ws = (char*)d_ws;
  size_t off = 0;
  auto alloc = [&](size_t bytes) -> void* {
    void* p = ws + off; off += (bytes + 255) & ~(size_t)255; return p;
  };
  unsigned short* bufA = (unsigned short*)alloc((size_t)Mpad * FDIM * 2);  // out1b
  unsigned short* bufB = (unsigned short*)alloc((size_t)Mpad * FDIM * 2);  // H1b, then H2b
  unsigned short* W1t  = (unsigned short*)alloc(256 * 256 * 2);
  unsigned short* W2t  = (unsigned short*)alloc(256 * 256 * 2);
  int*   zeros    = (int*)alloc((size_t)n * 2 * 4);   // deg | fill
  int*   deg      = zeros;
  int*   fill     = zeros + n;
  int*   tmp      = (int*)alloc((size_t)n * 4);
  int*   rowptr   = (int*)alloc((size_t)(n + 1) * 4);
  int*   partials = (int*)alloc(1024 * 4);
  int*   col      = (int*)alloc((size_t)(E + n) * 4);
  float* als1     = (float*)alloc((size_t)n * HEADS * 4);
  float* ald1     = (float*)alloc((size_t)n * HEADS * 4);
  float* als2     = (float*)alloc((size_t)n * 4);
  float* ald2     = (float*)alloc((size_t)n * 4);
  (void)ws_size;

  int nb = (n + 255) / 256;
  int nbx = Mpad / 128;             // 391
  hipMemsetAsync(zeros, 0, (size_t)n * 2 * 4, stream);

  // W transposes (tiny)
  k_wt<<<32, 256, 0, stream>>>(W1, W1t, W2, W2t);

  // fused: layer-1 GEMM (cast-staged A) + degree histogram (latency hides under MFMA)
  int histBlocks = (E + 255) / 256;
  k_g1h<<<2 * nbx + histBlocks, 256, 0, stream>>>(x, W1t, bufB, n, nbx, dstIdx, deg, E);

  // CSR scans
  k_scanA<<<nb, 256, 0, stream>>>(deg, tmp, partials, n);
  k_scanC<<<nb, 256, 0, stream>>>(tmp, deg, partials, rowptr, n, nb);

  // fused: XCD-partitioned fill + layer-1 logits
  int ga = (n + 3) / 4;
  int fillChunks = (E + n + CPB - 1) / CPB;
  int fillB = fillChunks * 8;
  k_fillal4<<<fillB + ga, 256, 0, stream>>>(srcIdx, dstIdx, rowptr, fill, col, E, n, fillB,
                                            bufB, as1, ad1, als1, ald1);

  int nA = 25000;                       // split point (multiple of 4)
  int gaA = nA / 4, gaB = (n - nA + 3) / 4;
  k_agg1<<<gaA, 256, 0, stream>>>(bufB, als1, ald1, rowptr, col, b1, bufA, 0, nA);
  k_agg1<<<gaB, 256, 0, stream>>>(bufB, als1, ald1, rowptr, col, b1, bufA, nA, n);
  // layer 2
  dim3 gg(nbx, 2);
  k_gemm<<<gg, 256, 0, stream>>>(bufA, W2t, bufB);                           // H2b
  k_al1<<<ga, 256, 0, stream>>>(bufB, as2, ad2, als2, ald2, n);
  k_agg2<<<gaA, 256, 0, stream>>>(bufB, als2, ald2, rowptr, col, b2, out, 0, nA);
  k_agg2<<<gaB, 256, 0, stream>>>(bufB, als2, ald2, rowptr, col, b2, out, nA, n);
}